// Round 7
// baseline (83.035 us; speedup 1.0000x reference)
//
#include <hip/hip_runtime.h>
#include <math.h>

#define KDIM 32
#define MDIM 256
#define NDIM 2048
#define Z_TOL 1e-6f   // removal threshold (reference semantics)
#define W_TOL 1e-3f   // add threshold (hysteresis: kills z/w deadband cycling,
                      // since w_j = d_j*z_j with d_j <= max diag(AtA) ~ 330 < 1000;
                      // solution shift <= W_TOL/lambda_min ~ 1e-5 << 3e-3)

// ---------------- helpers ----------------
__device__ __forceinline__ float lane_bcast(float x, int lane) {
  return __int_as_float(__builtin_amdgcn_readlane(__float_as_int(x), lane));
}
__device__ __forceinline__ float rcp_newton(float x) {
  float r;
  asm("v_rcp_f32 %0, %1" : "=v"(r) : "v"(x));
  r = r * (2.0f - x * r);  // one Newton step (shared LU only)
  return r;
}
__device__ __forceinline__ float rcp_fast(float x) {
  float r;
  asm("v_rcp_f32 %0, %1" : "=v"(r) : "v"(x));
  return r;  // ~1 ulp; fine vs 3e-3 threshold (kappa(AtA) ~ 56)
}

// ---------------- AtA partials: 8 blocks, each reduces 32 rows of A ------------
__global__ __launch_bounds__(1024) void ata_partial(const float* __restrict__ A,
                                                    float* __restrict__ part) {
  __shared__ float As[32 * KDIM];  // 4 KB slice
  const int t = threadIdx.x, g = blockIdx.x;
  As[t] = A[g * 32 * KDIM + t];  // coalesced
  __syncthreads();
  const int i = t >> 5, j = t & 31;
  float acc = 0.f;
#pragma unroll
  for (int mm = 0; mm < 32; ++mm)
    acc = fmaf(As[mm * KDIM + i], As[mm * KDIM + j], acc);  // bcast+consecutive: conflict-free
  part[g * 1024 + t] = acc;
}

// ---------------- sum partials -> AtA; LU-factor with inverted diagonal --------
__global__ __launch_bounds__(64) void lu_kernel(const float* __restrict__ part,
                                                float* __restrict__ AtA,
                                                float* __restrict__ LU) {
  __shared__ float AtAs[KDIM * 33];  // padded
  const int l = threadIdx.x;
  const int r = l & 31;
#pragma unroll
  for (int q4 = 0; q4 < 4; ++q4) {
    const int f4 = q4 * 64 + l;
    float4 s = {0.f, 0.f, 0.f, 0.f};
#pragma unroll
    for (int g = 0; g < 8; ++g) {
      const float4 v = reinterpret_cast<const float4*>(part)[g * 256 + f4];
      s.x += v.x; s.y += v.y; s.z += v.z; s.w += v.w;
    }
    reinterpret_cast<float4*>(AtA)[f4] = s;
    const int e = f4 * 4, row = e >> 5, col = e & 31;
    AtAs[row * 33 + col + 0] = s.x;
    AtAs[row * 33 + col + 1] = s.y;
    AtAs[row * 33 + col + 2] = s.z;
    AtAs[row * 33 + col + 3] = s.w;
  }
  __syncthreads();
  float m[KDIM];
#pragma unroll
  for (int c = 0; c < KDIM; ++c) m[c] = AtAs[r * 33 + c];
#pragma unroll
  for (int j = 0; j < KDIM; ++j) {
    const float inv = rcp_newton(lane_bcast(m[j], j));
    if (j < KDIM - 1) {
      const float f = (r > j) ? m[j] * inv : 0.f;
#pragma unroll
      for (int c = j + 1; c < KDIM; ++c) m[c] = fmaf(-f, lane_bcast(m[c], j), m[c]);
      if (r > j) m[j] = f;  // pack multiplier
    }
    if (r == j) m[j] = inv;  // pack inverted diagonal
  }
  if (l < 32) {
#pragma unroll
    for (int c = 0; c < KDIM; ++c) LU[r * KDIM + c] = m[c];
  }
}

// ---------------- per-column NNLS (fused Atb), one wave per column -------------
// Lane l owns row r=l&31; hi half mirrors lo so all branches are wave-uniform.
// Phase A: block principal pivoting (hysteresis W_TOL) — typically 2-4 solves.
// Phase B (rare stragglers): Lawson-Hanson restart (argmax add + alpha inner),
// provably finite since add-hysteresis guarantees z_new > Z_TOL => alpha > 0.
// One solve() call site; all-register GE with readlane broadcasts; inactive
// columns are exact no-ops and skipped via wave-uniform scalar branches.
__global__ __launch_bounds__(64, 2) void nnls_kernel(const float* __restrict__ A,
                                                     const float* __restrict__ AtA_g,
                                                     const float* __restrict__ LU_g,
                                                     const float* __restrict__ X,
                                                     float* __restrict__ S) {
  const int l = threadIdx.x;
  const int r = l & 31;
  const int n = blockIdx.x;

  // ---- Atb = A^T X[:, n] ----
  float x4[4];
#pragma unroll
  for (int q = 0; q < 4; ++q) x4[q] = X[(q * 64 + l) * NDIM + n];
  float cur[KDIM];
#pragma unroll
  for (int k = 0; k < KDIM; ++k) cur[k] = 0.f;
#pragma unroll
  for (int q = 0; q < 4; ++q) {
    const int m = q * 64 + l;
#pragma unroll
    for (int qq = 0; qq < 8; ++qq) {
      const float4 a4 = reinterpret_cast<const float4*>(A + m * KDIM)[qq];
      cur[4 * qq + 0] = fmaf(a4.x, x4[q], cur[4 * qq + 0]);
      cur[4 * qq + 1] = fmaf(a4.y, x4[q], cur[4 * qq + 1]);
      cur[4 * qq + 2] = fmaf(a4.z, x4[q], cur[4 * qq + 2]);
      cur[4 * qq + 3] = fmaf(a4.w, x4[q], cur[4 * qq + 3]);
    }
  }
#pragma unroll
  for (int k = 0; k < KDIM; ++k) cur[k] += __shfl_xor(cur[k], 32);
#pragma unroll
  for (int o = 16; o >= 1; o >>= 1) {
#pragma unroll
    for (int i = 0; i < o; ++i) {
      const bool hi = (l & o) != 0;
      const float a = cur[i], b = cur[i + o];
      const float mine = hi ? b : a;
      const float send = hi ? a : b;
      cur[i] = mine + __shfl_xor(send, o);
    }
  }
  const float atb = cur[0];  // Atb[r], mirrored in hi half

  // ---- shared AtA row + LU row ----
  float ata[KDIM], lu[KDIM];
#pragma unroll
  for (int q = 0; q < KDIM / 4; ++q) {
    const float4 v = reinterpret_cast<const float4*>(AtA_g + r * KDIM)[q];
    ata[4 * q + 0] = v.x; ata[4 * q + 1] = v.y; ata[4 * q + 2] = v.z; ata[4 * q + 3] = v.w;
    const float4 u = reinterpret_cast<const float4*>(LU_g + r * KDIM)[q];
    lu[4 * q + 0] = u.x; lu[4 * q + 1] = u.y; lu[4 * q + 2] = u.z; lu[4 * q + 3] = u.w;
  }

  // masked solve, registers + readlane; inactive cols/rows skipped (exact no-ops)
  auto solve = [&](unsigned int Pm) -> float {
    const bool actl = (Pm >> r) & 1u;
    float m[KDIM];
#pragma unroll
    for (int c = 0; c < KDIM; ++c)
      m[c] = (actl && ((Pm >> c) & 1u)) ? ata[c] : ((r == c) ? 1.f : 0.f);
    float rhs = actl ? atb : 0.f;
#pragma unroll
    for (int j = 0; j < KDIM; ++j) {
      if ((Pm >> j) & 1u) {
        const float inv = rcp_fast(lane_bcast(m[j], j));
        if (j < KDIM - 1) {
          const float f = (r > j) ? m[j] * inv : 0.f;
#pragma unroll
          for (int c = j + 1; c < KDIM; ++c)
            if ((Pm >> c) & 1u)  // inactive c: identity col, update is exact no-op
              m[c] = fmaf(-f, lane_bcast(m[c], j), m[c]);
          rhs = fmaf(-f, lane_bcast(rhs, j), rhs);
        }
        if (r == j) m[j] = inv;  // stash reciprocal for back-sub
      }
    }
    float zz = 0.f;
#pragma unroll
    for (int j = KDIM - 1; j >= 0; --j) {
      if ((Pm >> j) & 1u) {
        const float xj = lane_bcast(rhs, j) * lane_bcast(m[j], j);
        if (r == j) zz = xj;
        if (r < j) rhs = fmaf(-m[j], xj, rhs);
      }
    }
    return zz;
  };

  // ---- init: all-active shared-LU fast path (Atb > 0 in practice) ----
  unsigned int P;
  float z;
  {
    const unsigned long long b0 = __ballot(atb > Z_TOL);
    const unsigned int P0 = (unsigned int)(b0 & 0xffffffffull);
    if (P0 == 0xffffffffu) {
      P = P0;
      float rhs = atb;
#pragma unroll
      for (int j = 0; j < KDIM - 1; ++j) {
        const float fj = (r > j) ? lu[j] : 0.f;
        rhs = fmaf(-fj, lane_bcast(rhs, j), rhs);
      }
      z = 0.f;
#pragma unroll
      for (int j = KDIM - 1; j >= 0; --j) {
        const float xj = lane_bcast(rhs, j) * lane_bcast(lu[j], j);  // diag pre-inverted
        if (r == j) z = xj;
        const float uj = (r < j) ? lu[j] : 0.f;
        rhs = fmaf(-uj, xj, rhs);
      }
    } else {
      P = 0u;
      z = 0.f;
    }
  }

  // ---- main loop: BPP phase, then LH fallback; single solve() site ----
  float sv = 0.f;          // LH feasible iterate / final result
  int bppleft = 6;
  bool lh = false, pick = true, done = false;
  for (int it = 0; it < 160 && !done; ++it) {
    bool dosolve = true;
    if (!lh) {
      const bool act = (P >> r) & 1u;
      const float zm = act ? z : 0.f;
      float w = atb;
#pragma unroll
      for (int c = 0; c < KDIM; ++c)
        if ((P >> c) & 1u)  // z=0 on inactive: skip
          w = fmaf(-ata[c], lane_bcast(zm, c), w);
      const unsigned int bad = (unsigned int)(__ballot(act && (z <= Z_TOL)) & 0xffffffffull);
      const unsigned int viol = (unsigned int)(__ballot((!act) && (w > W_TOL)) & 0xffffffffull);
      const unsigned int u = bad | viol;
      if (u == 0u) {
        sv = zm;  // KKT (hysteresis) satisfied
        done = true; dosolve = false;
      } else if (bppleft > 0) {
        --bppleft;
        P = (P & ~bad) | viol;
      } else {
        lh = true; pick = true; P = 0u; sv = 0.f; z = 0.f;  // LH restart
        dosolve = false;
      }
    } else if (pick) {
      // LH outer: w from feasible s; argmax over inactive
      float w = atb;
#pragma unroll
      for (int c = 0; c < KDIM; ++c)
        if ((P >> c) & 1u)  // s=0 on inactive: skip
          w = fmaf(-ata[c], lane_bcast(sv, c), w);
      const bool inact = !((P >> r) & 1u);
      float wv = inact ? w : -INFINITY;
      int wi = inact ? r : KDIM;
#pragma unroll
      for (int off = 16; off >= 1; off >>= 1) {
        const float ow = __shfl_xor(wv, off);
        const int oi = __shfl_xor(wi, off);
        if (ow > wv || (ow == wv && oi < wi)) { wv = ow; wi = oi; }
      }
      if (!(wv > W_TOL)) {
        done = true; dosolve = false;  // result already in sv
      } else {
        P |= (1u << __builtin_amdgcn_readfirstlane(wi));
      }
    } else {
      // LH inner: alpha line search toward z, remove crossers
      const bool act = (P >> r) & 1u;
      const bool bad = act && (z <= Z_TOL);
      const float denom = sv - z;
      float ratio = bad ? (sv / ((denom != 0.f) ? denom : 1.f)) : INFINITY;
#pragma unroll
      for (int off = 16; off >= 1; off >>= 1) ratio = fminf(ratio, __shfl_xor(ratio, off));
      sv = fmaf(ratio, z - sv, sv);
      const bool keep = act && (sv > Z_TOL);
      P = (unsigned int)(__ballot(keep) & 0xffffffffull);
      sv = keep ? sv : 0.f;
    }
    if (dosolve) {
      z = solve(P);
      if (lh) {
        const bool bad2 = ((P >> r) & 1u) && (z <= Z_TOL);
        if ((__ballot(bad2) & 0xffffffffull) != 0ull) {
          pick = false;          // need alpha step
        } else {
          sv = ((P >> r) & 1u) ? z : 0.f;  // accept
          pick = true;
        }
      }
    }
  }

  if (l < KDIM) S[r * NDIM + n] = sv;
}

extern "C" void kernel_launch(void* const* d_in, const int* in_sizes, int n_in,
                              void* d_out, int out_size, void* d_ws, size_t ws_size,
                              hipStream_t stream) {
  const float* X = (const float*)d_in[0];  // [256, 2048]
  const float* A = (const float*)d_in[1];  // [256, 32]
  float* S = (float*)d_out;                // [32, 2048]
  float* AtA = (float*)d_ws;               // 1024 floats
  float* LU = AtA + KDIM * KDIM;           // 1024 floats
  float* part = LU + KDIM * KDIM;          // 8*1024 floats

  ata_partial<<<8, 1024, 0, stream>>>(A, part);
  lu_kernel<<<1, 64, 0, stream>>>(part, AtA, LU);
  nnls_kernel<<<NDIM, 64, 0, stream>>>(A, AtA, LU, X, S);
}

// Round 8
// 43.447 us; speedup vs baseline: 1.9112x; 1.9112x over previous
//
#include <hip/hip_runtime.h>
#include <math.h>

#define KDIM 32
#define MDIM 256
#define NDIM 2048
#define Z_TOL 1e-6f   // removal threshold (reference semantics)
#define W_TOL 1e-3f   // add threshold (hysteresis: kills z/w deadband cycling,
                      // since w_j = d_j*z_j with d_j <= max diag(AtA) ~ 330 < 1000;
                      // solution shift <= W_TOL/lambda_min ~ 1e-5 << 3e-3)

// ---------------- helpers ----------------
__device__ __forceinline__ float lane_bcast(float x, int lane) {
  return __int_as_float(__builtin_amdgcn_readlane(__float_as_int(x), lane));
}
__device__ __forceinline__ float rcp_newton(float x) {
  float r;
  asm("v_rcp_f32 %0, %1" : "=v"(r) : "v"(x));
  r = r * (2.0f - x * r);  // one Newton step (shared inverse only)
  return r;
}
__device__ __forceinline__ float rcp_fast(float x) {
  float r;
  asm("v_rcp_f32 %0, %1" : "=v"(r) : "v"(x));
  return r;  // ~1 ulp; fine vs 3e-3 threshold (kappa(AtA) ~ 56)
}

// ---------------- AtA partials: 8 blocks, each reduces 32 rows of A ------------
__global__ __launch_bounds__(1024) void ata_partial(const float* __restrict__ A,
                                                    float* __restrict__ part) {
  __shared__ float As[32 * KDIM];  // 4 KB slice
  const int t = threadIdx.x, g = blockIdx.x;
  As[t] = A[g * 32 * KDIM + t];  // coalesced
  __syncthreads();
  const int i = t >> 5, j = t & 31;
  float acc = 0.f;
#pragma unroll
  for (int mm = 0; mm < 32; ++mm)
    acc = fmaf(As[mm * KDIM + i], As[mm * KDIM + j], acc);  // bcast+consecutive: conflict-free
  part[g * 1024 + t] = acc;
}

// ---------------- sum partials -> AtA; full inverse via Gauss-Jordan ----------
// One wave. Lane r holds row r of [M | G], G init = I. Row ops reduce M to
// diag D; then M^-1 row r = (1/D_r) * G row r.
__global__ __launch_bounds__(64) void inv_kernel(const float* __restrict__ part,
                                                 float* __restrict__ AtA,
                                                 float* __restrict__ Ainv) {
  __shared__ float AtAs[KDIM * 33];  // padded
  const int l = threadIdx.x;
  const int r = l & 31;
#pragma unroll
  for (int q4 = 0; q4 < 4; ++q4) {
    const int f4 = q4 * 64 + l;
    float4 s = {0.f, 0.f, 0.f, 0.f};
#pragma unroll
    for (int g = 0; g < 8; ++g) {
      const float4 v = reinterpret_cast<const float4*>(part)[g * 256 + f4];
      s.x += v.x; s.y += v.y; s.z += v.z; s.w += v.w;
    }
    reinterpret_cast<float4*>(AtA)[f4] = s;
    const int e = f4 * 4, row = e >> 5, col = e & 31;
    AtAs[row * 33 + col + 0] = s.x;
    AtAs[row * 33 + col + 1] = s.y;
    AtAs[row * 33 + col + 2] = s.z;
    AtAs[row * 33 + col + 3] = s.w;
  }
  __syncthreads();
  float m[KDIM], g[KDIM];
#pragma unroll
  for (int c = 0; c < KDIM; ++c) {
    m[c] = AtAs[r * 33 + c];
    g[c] = (r == c) ? 1.f : 0.f;
  }
  float myinv = 0.f;
#pragma unroll
  for (int j = 0; j < KDIM; ++j) {
    const float inv = rcp_newton(lane_bcast(m[j], j));
    const float f = (r != j) ? m[j] * inv : 0.f;
#pragma unroll
    for (int c = j + 1; c < KDIM; ++c) m[c] = fmaf(-f, lane_bcast(m[c], j), m[c]);
#pragma unroll
    for (int c = 0; c < KDIM; ++c) g[c] = fmaf(-f, lane_bcast(g[c], j), g[c]);
    if (r == j) myinv = inv;
  }
  if (l < 32) {
#pragma unroll
    for (int c = 0; c < KDIM; ++c) Ainv[r * KDIM + c] = myinv * g[c];
  }
}

// ---------------- per-column NNLS (fused Atb), one wave per column -------------
// Lane l owns row r=l&31; hi half mirrors lo so all branches are wave-uniform.
// Init: z = Ainv @ Atb (shared inverse, no serial chain). Then block principal
// pivoting (hysteresis) + Murty least-index safeguard. Masked solves are
// all-register Gauss-Jordan (no back-substitution): per active pivot j,
// f=(r!=j)?m[j]*inv:0 eliminates the whole column; z = rhs * myinv at the end.
__global__ __launch_bounds__(64, 2) void nnls_kernel(const float* __restrict__ A,
                                                     const float* __restrict__ AtA_g,
                                                     const float* __restrict__ Ainv_g,
                                                     const float* __restrict__ X,
                                                     float* __restrict__ S) {
  const int l = threadIdx.x;
  const int r = l & 31;
  const int n = blockIdx.x;

  // ---- Atb = A^T X[:, n] ----
  float x4[4];
#pragma unroll
  for (int q = 0; q < 4; ++q) x4[q] = X[(q * 64 + l) * NDIM + n];
  float cur[KDIM];
#pragma unroll
  for (int k = 0; k < KDIM; ++k) cur[k] = 0.f;
#pragma unroll
  for (int q = 0; q < 4; ++q) {
    const int m = q * 64 + l;
#pragma unroll
    for (int qq = 0; qq < 8; ++qq) {
      const float4 a4 = reinterpret_cast<const float4*>(A + m * KDIM)[qq];
      cur[4 * qq + 0] = fmaf(a4.x, x4[q], cur[4 * qq + 0]);
      cur[4 * qq + 1] = fmaf(a4.y, x4[q], cur[4 * qq + 1]);
      cur[4 * qq + 2] = fmaf(a4.z, x4[q], cur[4 * qq + 2]);
      cur[4 * qq + 3] = fmaf(a4.w, x4[q], cur[4 * qq + 3]);
    }
  }
#pragma unroll
  for (int k = 0; k < KDIM; ++k) cur[k] += __shfl_xor(cur[k], 32);
#pragma unroll
  for (int o = 16; o >= 1; o >>= 1) {
#pragma unroll
    for (int i = 0; i < o; ++i) {
      const bool hi = (l & o) != 0;
      const float a = cur[i], b = cur[i + o];
      const float mine = hi ? b : a;
      const float send = hi ? a : b;
      cur[i] = mine + __shfl_xor(send, o);
    }
  }
  const float atb = cur[0];  // Atb[r], mirrored in hi half

  // ---- shared AtA row + Ainv row ----
  float ata[KDIM], ainv[KDIM];
#pragma unroll
  for (int q = 0; q < KDIM / 4; ++q) {
    const float4 v = reinterpret_cast<const float4*>(AtA_g + r * KDIM)[q];
    ata[4 * q + 0] = v.x; ata[4 * q + 1] = v.y; ata[4 * q + 2] = v.z; ata[4 * q + 3] = v.w;
    const float4 u = reinterpret_cast<const float4*>(Ainv_g + r * KDIM)[q];
    ainv[4 * q + 0] = u.x; ainv[4 * q + 1] = u.y; ainv[4 * q + 2] = u.z; ainv[4 * q + 3] = u.w;
  }

  // masked solve via Gauss-Jordan: (AtA o PP^T + diag(1-P)) z = P o Atb.
  // Registers + readlane only; inactive pivot steps skipped (wave-uniform).
  auto solve = [&](unsigned int Pm) -> float {
    const bool actl = (Pm >> r) & 1u;
    float m[KDIM];
#pragma unroll
    for (int c = 0; c < KDIM; ++c)
      m[c] = (actl && ((Pm >> c) & 1u)) ? ata[c] : ((r == c) ? 1.f : 0.f);
    float rhs = actl ? atb : 0.f;
    float myinv = 0.f;
#pragma unroll
    for (int j = 0; j < KDIM; ++j) {
      if ((Pm >> j) & 1u) {
        const float inv = rcp_fast(lane_bcast(m[j], j));
        const float f = (r != j) ? m[j] * inv : 0.f;
#pragma unroll
        for (int c = j + 1; c < KDIM; ++c) m[c] = fmaf(-f, lane_bcast(m[c], j), m[c]);
        rhs = fmaf(-f, lane_bcast(rhs, j), rhs);
        if (r == j) myinv = inv;
      }
    }
    return rhs * myinv;  // diag untouched after its own pivot step
  };

  // ---- init: all-active fast path z = Ainv @ Atb (no serial chain) ----
  unsigned int P;
  float z;
  {
    const unsigned long long b0 = __ballot(atb > Z_TOL);
    const unsigned int P0 = (unsigned int)(b0 & 0xffffffffull);
    if (P0 == 0xffffffffu) {
      P = P0;
      float zi = 0.f;
#pragma unroll
      for (int c = 0; c < KDIM; ++c) zi = fmaf(ainv[c], lane_bcast(atb, c), zi);
      z = zi;
    } else {
      P = 0u;
      z = 0.f;
    }
  }

  // ---- block principal pivoting + Murty least-index safeguard + hysteresis ----
  int ninf_best = 1000, budget = 3;
  for (int it = 0; it < 64; ++it) {
    const bool act = (P >> r) & 1u;
    const float zm = act ? z : 0.f;
    float w = atb;
#pragma unroll
    for (int c = 0; c < KDIM; ++c) w = fmaf(-ata[c], lane_bcast(zm, c), w);
    const unsigned int bad = (unsigned int)(__ballot(act && (z <= Z_TOL)) & 0xffffffffull);
    const unsigned int viol = (unsigned int)(__ballot((!act) && (w > W_TOL)) & 0xffffffffull);
    const unsigned int u = bad | viol;
    if (u == 0u) break;  // hysteresis-KKT satisfied (uniform)
    const int ninf = __popc(u);
    bool useblock;
    if (ninf < ninf_best) { ninf_best = ninf; budget = 3; useblock = true; }
    else if (budget > 0) { --budget; useblock = true; }
    else { useblock = false; }
    if (useblock) {
      P = (P & ~bad) | viol;
    } else {
      const int j = __ffs(u) - 1;  // Murty: least-index single flip
      P ^= (1u << j);
    }
    z = solve(P);
  }

  if (l < KDIM) S[r * NDIM + n] = ((P >> r) & 1u) ? z : 0.f;
}

extern "C" void kernel_launch(void* const* d_in, const int* in_sizes, int n_in,
                              void* d_out, int out_size, void* d_ws, size_t ws_size,
                              hipStream_t stream) {
  const float* X = (const float*)d_in[0];  // [256, 2048]
  const float* A = (const float*)d_in[1];  // [256, 32]
  float* S = (float*)d_out;                // [32, 2048]
  float* AtA = (float*)d_ws;               // 1024 floats
  float* Ainv = AtA + KDIM * KDIM;         // 1024 floats
  float* part = Ainv + KDIM * KDIM;        // 8*1024 floats

  ata_partial<<<8, 1024, 0, stream>>>(A, part);
  inv_kernel<<<1, 64, 0, stream>>>(part, AtA, Ainv);
  nnls_kernel<<<NDIM, 64, 0, stream>>>(A, AtA, Ainv, X, S);
}